// Round 6
// baseline (410.650 us; speedup 1.0000x reference)
//
#include <hip/hip_runtime.h>
#include <hip/hip_bf16.h>
#include <hip/hip_fp16.h>

#define NN 100000
#define NE 1600000
#define NNP (NN + 8)                 // padded rows per slice (row NN = zeros)
#define NCHUNK ((NN + 127) / 128)   // 782 (gemm row chunks of 128)
#define NPB 512                      // nodes per bucket (pow2, shift 9)
#define NB 256                       // bucket slots (196 active)
#define CHUNK 8192                   // edges per bscatter block
#define NCH ((NE + CHUNK - 1) / CHUNK)  // 196

typedef __attribute__((ext_vector_type(8))) short short8;
typedef __attribute__((ext_vector_type(4))) float float4v;
typedef __attribute__((ext_vector_type(2))) float float2v;

#define SLS ((size_t)NNP * 16)       // slice stride in ushorts (32 B/node rows)
#define NN32 ((size_t)NN * 32)       // pslc slice stride in ushorts

__device__ __forceinline__ unsigned short f2bf(float f) {
    unsigned int b = __float_as_uint(f);
    return (unsigned short)((b + 0x7fffu + ((b >> 16) & 1u)) >> 16);
}
__device__ __forceinline__ unsigned int pack_bf16(float lo, float hi) {
    return (unsigned int)f2bf(lo) | ((unsigned int)f2bf(hi) << 16);
}
__device__ __forceinline__ unsigned char f2fp8(float v) {
    int r = __builtin_amdgcn_cvt_pk_fp8_f32(v, v, 0, false);
    return (unsigned char)(r & 0xff);
}
__device__ __forceinline__ unsigned short pack2fp8(float lo, float hi) {
    int r = __builtin_amdgcn_cvt_pk_fp8_f32(lo, hi, 0, false);
    return (unsigned short)(r & 0xffff);
}
__device__ __forceinline__ float h2f(unsigned short u) {
    return __half2float(__ushort_as_half(u));
}

// ---- fused prep: xconv (0..3124), wconv (3125..3252), bcount (3253..3508), zero-rows (3509) ----
__global__ void k_prep(const float* x, const float* W1l, const float* W1r,
                       const float* W2l, const float* W2r, const int* ei,
                       unsigned int* axb_u, unsigned short* xf8s, unsigned short* wb1,
                       unsigned short* wb2, int* bcnt, unsigned short* g2z) {
    __shared__ int hh[NB];
    int b = blockIdx.x, t = threadIdx.x;
    if (b < 3125) {
#pragma unroll
        for (int k = 0; k < 8; k++) {
            int tt = b * 2048 + k * 256 + t;      // < 6.4M = NN*64
            int node = tt >> 6, i = tt & 63;
            float2 v = ((const float2*)x)[tt];
            axb_u[(size_t)node * 128 + 64 + i] = pack_bf16(v.x, v.y);
            // slice-major fp8: slice = i>>4, within-slice ushort = i&15
            xf8s[(size_t)(i >> 4) * SLS + (size_t)node * 16 + (i & 15)] = pack2fp8(v.x, v.y);
        }
    } else if (b < 3253) {
        int i = (b - 3125) * 256 + t;         // < 32768
        int r1 = i >> 7, c1 = i & 127;        // W1l/W1r are 256x128
        wb1[r1 * 256 + c1]       = f2bf(W1l[i]);
        wb1[r1 * 256 + 128 + c1] = f2bf(W1r[i]);
        wb2[i]         = f2bf(W2l[i]);        // 128x256, k contiguous
        wb2[32768 + i] = f2bf(W2r[i]);
    } else if (b < 3509) {
        hh[t] = 0;
        __syncthreads();
        int e0 = (b - 3253) * 6250;           // 256 * 6250 = NE exactly
        for (int e = e0 + t; e < e0 + 6250; e += 256)
            atomicAdd(&hh[ei[NE + e] >> 9], 1);
        __syncthreads();
        if (hh[t]) atomicAdd(&bcnt[t], hh[t]);
    } else {
        // zero padding row (index NN) of each slice of xf8s and g2
        if (t < 64) xf8s[(size_t)(t >> 4) * SLS + (size_t)NN * 16 + (t & 15)] = 0;
        else if (t < 128) {
            int q = t - 64;
            g2z[(size_t)(q >> 4) * SLS + (size_t)NN * 16 + (q & 15)] = 0;
        }
    }
}

__global__ void k_bscan(const int* bcnt, int* boff, int* bcur) {
    __shared__ int s[NB];
    int t = threadIdx.x;
    int v = bcnt[t];
    s[t] = v;
    __syncthreads();
    for (int d = 1; d < NB; d <<= 1) {
        int val = (t >= d) ? s[t - d] : 0;
        __syncthreads();
        s[t] += val;
        __syncthreads();
    }
    boff[t + 1] = s[t];
    if (t == 0) boff[0] = 0;
    bcur[t] = s[t] - v;   // exclusive
}

// pairs packed: bits[0:17)=row, bits[17:26)=col&511 (bucket-local)
__global__ __launch_bounds__(256) void k_bscatter(const int* ei, int* bcur, unsigned int* pairs) {
    __shared__ unsigned int buf[CHUNK];   // 32 KB
    __shared__ int cnt[NB];
    __shared__ int lbase[NB];
    __shared__ int lcur[NB];
    __shared__ int gpos[NB];
    int t = threadIdx.x;
    int e0 = blockIdx.x * CHUNK;
    int nedge = NE - e0; if (nedge > CHUNK) nedge = CHUNK;
    cnt[t] = 0;
    __syncthreads();
    for (int i = t; i < nedge; i += 256)
        atomicAdd(&cnt[ei[NE + e0 + i] >> 9], 1);
    __syncthreads();
    int v = cnt[t];
    lcur[t] = v;
    __syncthreads();
    for (int d = 1; d < NB; d <<= 1) {
        int val = (t >= d) ? lcur[t - d] : 0;
        __syncthreads();
        lcur[t] += val;
        __syncthreads();
    }
    lbase[t] = lcur[t] - v;
    gpos[t] = atomicAdd(&bcur[t], v);
    __syncthreads();
    lcur[t] = lbase[t];
    __syncthreads();
    for (int i = t; i < nedge; i += 256) {
        int r = ei[e0 + i], c = ei[NE + e0 + i];
        int b = c >> 9;
        int p = atomicAdd(&lcur[b], 1);
        buf[p] = (unsigned)r | ((unsigned)(c & 511) << 17);
    }
    __syncthreads();
    // coalesced flush: wave wv handles buckets wv, wv+4, ...; lanes stride inside
    int wv = t >> 6, lane = t & 63;
    for (int b = wv; b < NB; b += 4) {
        int n = cnt[b], lb = lbase[b], gp = gpos[b];
        for (int i = lane; i < n; i += 64)
            pairs[gp + i] = buf[lb + i];
    }
}

// builds CSR; additionally writes dense first-32 neighbor table csr32[n][32] (if non-null)
__global__ __launch_bounds__(256) void k_build(const unsigned int* pairs, const int* boff,
                                               int* off, int* deg, int* csr, int* csr32) {
    __shared__ int ldeg[NPB];
    __shared__ int lcur[NPB];
    __shared__ int lini[NPB];
    __shared__ int sscan[256];
    int b = blockIdx.x;
    int nbase = b * NPB;
    if (nbase >= NN) return;
    int t = threadIdx.x;
    int base = boff[b], cntb = boff[b + 1] - base;
    ldeg[t] = 0; ldeg[t + 256] = 0;
    __syncthreads();
    for (int i = t; i < cntb; i += 256) {
        unsigned int pr = pairs[base + i];
        atomicAdd(&ldeg[pr >> 17], 1);
    }
    __syncthreads();
    int d0 = ldeg[2 * t], d1 = ldeg[2 * t + 1];
    int v = d0 + d1;
    sscan[t] = v;
    __syncthreads();
    for (int d = 1; d < 256; d <<= 1) {
        int val = (t >= d) ? sscan[t - d] : 0;
        __syncthreads();
        sscan[t] += val;
        __syncthreads();
    }
    int ex = sscan[t] - v;
    lcur[2 * t] = ex;      lcur[2 * t + 1] = ex + d0;
    lini[2 * t] = ex;      lini[2 * t + 1] = ex + d0;
    __syncthreads();
    int nloc = NN - nbase; if (nloc > NPB) nloc = NPB;
    for (int ln = t; ln < nloc; ln += 256) {
        off[nbase + ln] = base + lcur[ln];
        deg[nbase + ln] = ldeg[ln];
    }
    __syncthreads();
    if (csr32) {
        for (int i = t; i < cntb; i += 256) {
            unsigned int pr = pairs[base + i];
            int nd = pr >> 17;
            int p = atomicAdd(&lcur[nd], 1);
            int src = (int)(pr & 0x1FFFFu);
            csr[base + p] = src;
            int rk = p - lini[nd];
            if (rk < 32) csr32[(size_t)(nbase + nd) * 32 + rk] = src;
        }
    } else {
        for (int i = t; i < cntb; i += 256) {
            unsigned int pr = pairs[base + i];
            int p = atomicAdd(&lcur[pr >> 17], 1);
            csr[base + p] = (int)(pr & 0x1FFFFu);
        }
    }
}

// ---- agg1 (XCD-pinned feature slices): mean of xf8s slice over neighbors -> axb (bf16) ----
// slice s = (bid&7)>>1 pinned to XCD pair {2s,2s+1}; per-slice gather array = 3.2 MB (L2-fit).
// 16-lane group per node; lane = feature-pair within slice; streams are nontemporal.
__global__ __launch_bounds__(512) void k_agg1(const unsigned short* xs, const int* off,
                                              const int* deg, const int* csr, const int* csr32,
                                              unsigned int* axb_w) {
    int bid = blockIdx.x;
    int s = (bid & 7) >> 1;
    int k = ((bid >> 3) << 1) | (bid & 1);
    if (k >= 3125) return;                    // 3125*32 = NN exactly
    int t = threadIdx.x;
    int lane = t & 63;
    int grp = lane >> 4, l16 = lane & 15;
    int node = k * 32 + (t >> 6) * 4 + grp;   // < NN
    const unsigned short* gs = xs + (size_t)s * SLS;
    int d = deg[node];
    const int* c32 = csr32 + (size_t)node * 32;
    int e0 = __builtin_nontemporal_load(c32 + l16);
    int e1 = __builtin_nontemporal_load(c32 + 16 + l16);
    int dm = d < 32 ? d : 32;
    float a0 = 0.f, a1 = 0.f;
#pragma unroll
    for (int slot = 0; slot < 32; slot++) {
        int idx = __shfl(slot < 16 ? e0 : e1, (grp << 4) | (slot & 15), 64);
        idx = (slot < dm) ? idx : NN;         // NN = zeroed pad row
        unsigned short u = gs[(size_t)idx * 16 + l16];
        float2v f = __builtin_amdgcn_cvt_pk_f32_fp8((unsigned int)u, false);
        a0 += f.x; a1 += f.y;
    }
    if (d > 32) {
        int st = off[node];
        for (int j = 32; j < d; j++) {
            int idx = csr[st + j];
            unsigned short u = gs[(size_t)idx * 16 + l16];
            float2v f = __builtin_amdgcn_cvt_pk_f32_fp8((unsigned int)u, false);
            a0 += f.x; a1 += f.y;
        }
    }
    float inv = 1.0f / (float)(d > 0 ? d : 1);
    __builtin_nontemporal_store(pack_bf16(a0 * inv, a1 * inv),
                                axb_w + (size_t)node * 128 + (s << 4) + l16);
}

// ---- agg2 (XCD-pinned feature slices): out = partial(f16,sliced) + mean of g2 slice ----
__global__ __launch_bounds__(512) void k_agg2(const unsigned short* g2, const int* off,
                                              const int* deg, const int* csr, const int* csr32,
                                              const unsigned short* pslc, float* out) {
    int bid = blockIdx.x;
    int s = (bid & 7) >> 1;
    int k = ((bid >> 3) << 1) | (bid & 1);
    if (k >= 3125) return;
    int t = threadIdx.x;
    int lane = t & 63;
    int grp = lane >> 4, l16 = lane & 15;
    int node = k * 32 + (t >> 6) * 4 + grp;
    const unsigned short* gs = g2 + (size_t)s * SLS;
    int d = deg[node];
    const int* c32 = csr32 + (size_t)node * 32;
    int e0 = __builtin_nontemporal_load(c32 + l16);
    int e1 = __builtin_nontemporal_load(c32 + 16 + l16);
    unsigned int pu = __builtin_nontemporal_load(
        (const unsigned int*)(pslc + (size_t)s * NN32 + (size_t)node * 32 + (l16 << 1)));
    int dm = d < 32 ? d : 32;
    float a0 = 0.f, a1 = 0.f;
#pragma unroll
    for (int slot = 0; slot < 32; slot++) {
        int idx = __shfl(slot < 16 ? e0 : e1, (grp << 4) | (slot & 15), 64);
        idx = (slot < dm) ? idx : NN;
        unsigned short u = gs[(size_t)idx * 16 + l16];
        float2v f = __builtin_amdgcn_cvt_pk_f32_fp8((unsigned int)u, false);
        a0 += f.x; a1 += f.y;
    }
    if (d > 32) {
        int st = off[node];
        for (int j = 32; j < d; j++) {
            int idx = csr[st + j];
            unsigned short u = gs[(size_t)idx * 16 + l16];
            float2v f = __builtin_amdgcn_cvt_pk_f32_fp8((unsigned int)u, false);
            a0 += f.x; a1 += f.y;
        }
    }
    float inv = 1.0f / (float)(d > 0 ? d : 1);
    float2v o;
    o.x = h2f((unsigned short)(pu & 0xffff)) + a0 * inv;
    o.y = h2f((unsigned short)(pu >> 16)) + a1 * inv;
    __builtin_nontemporal_store(o, (float2v*)(out + (size_t)node * 128 + (s << 5)) + l16);
}

// ---- GEMM1 (col-split, XCD-swizzled): 128 rows x 64 cols of relu(A@wb1^T + b1) -> H ----
#define BROW 264
#define GGRID (32 * ((NCHUNK + 7) / 8))   // 32*98 = 3136
__global__ __launch_bounds__(256, 4) void k_gemm1(const unsigned short* A, const unsigned short* wb,
                                                  const float* b1, unsigned short* H) {
    __shared__ unsigned short Bs[64 * BROW];   // 33 KB
    int t = threadIdx.x;
    int b = blockIdx.x;
    int chunk = (b & 7) + ((b >> 5) << 3);
    int cg = (b >> 3) & 3;
    if (chunk >= NCHUNK) return;
    {
        const short8* src = (const short8*)(wb + (size_t)cg * 64 * 256);
        short8* dst = (short8*)Bs;   // 33 granules per row
#pragma unroll
        for (int i = 0; i < 8; i++) {
            int gi = i * 256 + t;             // 2048 granules of 16B
            int r = gi >> 5, c = gi & 31;
            dst[r * 33 + c] = src[gi];
        }
    }
    __syncthreads();
    int wv = t >> 6, lane = t & 63;
    int mrow = lane & 15, quad = lane >> 4;
    int base = chunk * 128 + wv * 32;
    if (base >= NN) return;
    float bias[4];
#pragma unroll
    for (int ctl = 0; ctl < 4; ctl++) bias[ctl] = b1[cg * 64 + ctl * 16 + mrow];
    float4v acc[2][4];
#pragma unroll
    for (int h = 0; h < 2; h++)
#pragma unroll
        for (int ctl = 0; ctl < 4; ctl++) acc[h][ctl] = (float4v)(0.0f);
    const short8* a0p = (const short8*)(A + (size_t)(base + mrow) * 256);
    const short8* a1p = (const short8*)(A + (size_t)(base + 16 + mrow) * 256);
#pragma unroll
    for (int kk = 0; kk < 8; kk++) {
        short8 a0 = a0p[kk * 4 + quad];
        short8 a1 = a1p[kk * 4 + quad];
        int koff = kk * 32 + quad * 8;
#pragma unroll
        for (int ctl = 0; ctl < 4; ctl++) {
            short8 bfr = *(const short8*)(Bs + (ctl * 16 + mrow) * BROW + koff);
            acc[0][ctl] = __builtin_amdgcn_mfma_f32_16x16x32_bf16(a0, bfr, acc[0][ctl], 0, 0, 0);
            acc[1][ctl] = __builtin_amdgcn_mfma_f32_16x16x32_bf16(a1, bfr, acc[1][ctl], 0, 0, 0);
        }
    }
#pragma unroll
    for (int ctl = 0; ctl < 4; ctl++) {
        int col = cg * 64 + ctl * 16 + mrow;
#pragma unroll
        for (int h = 0; h < 2; h++)
#pragma unroll
            for (int r = 0; r < 4; r++) {
                int node = base + h * 16 + quad * 4 + r;
                float v = acc[h][ctl][r] + bias[ctl];
                H[(size_t)node * 256 + col] = f2bf(fmaxf(v, 0.f));
            }
    }
}

// ---- GEMM2 (col-split, XCD-swizzled): cg 0,1 -> g2 (fp8, slice-major); cg 2,3 -> pslc (f16) ----
__global__ __launch_bounds__(256, 4) void k_gemm2(const unsigned short* A, const unsigned short* wb,
                                                  const float* b2, unsigned char* g2b,
                                                  unsigned short* pslc) {
    __shared__ unsigned short Bs[64 * BROW];   // 33 KB
    int t = threadIdx.x;
    int b = blockIdx.x;
    int chunk = (b & 7) + ((b >> 5) << 3);
    int cg = (b >> 3) & 3;
    if (chunk >= NCHUNK) return;
    {
        const short8* src = (const short8*)(wb + (size_t)cg * 64 * 256);
        short8* dst = (short8*)Bs;
#pragma unroll
        for (int i = 0; i < 8; i++) {
            int gi = i * 256 + t;
            int r = gi >> 5, c = gi & 31;
            dst[r * 33 + c] = src[gi];
        }
    }
    __syncthreads();
    int wv = t >> 6, lane = t & 63;
    int mrow = lane & 15, quad = lane >> 4;
    int base = chunk * 128 + wv * 32;
    if (base >= NN) return;
    float bias[4];
#pragma unroll
    for (int ctl = 0; ctl < 4; ctl++)
        bias[ctl] = (cg >= 2) ? b2[cg * 64 + ctl * 16 + mrow - 128] : 0.f;
    float4v acc[2][4];
#pragma unroll
    for (int h = 0; h < 2; h++)
#pragma unroll
        for (int ctl = 0; ctl < 4; ctl++) acc[h][ctl] = (float4v)(0.0f);
    const short8* a0p = (const short8*)(A + (size_t)(base + mrow) * 256);
    const short8* a1p = (const short8*)(A + (size_t)(base + 16 + mrow) * 256);
#pragma unroll
    for (int kk = 0; kk < 8; kk++) {
        short8 a0 = a0p[kk * 4 + quad];
        short8 a1 = a1p[kk * 4 + quad];
        int koff = kk * 32 + quad * 8;
#pragma unroll
        for (int ctl = 0; ctl < 4; ctl++) {
            short8 bfr = *(const short8*)(Bs + (ctl * 16 + mrow) * BROW + koff);
            acc[0][ctl] = __builtin_amdgcn_mfma_f32_16x16x32_bf16(a0, bfr, acc[0][ctl], 0, 0, 0);
            acc[1][ctl] = __builtin_amdgcn_mfma_f32_16x16x32_bf16(a1, bfr, acc[1][ctl], 0, 0, 0);
        }
    }
    if (cg < 2) {
#pragma unroll
        for (int ctl = 0; ctl < 4; ctl++) {
            int col = cg * 64 + ctl * 16 + mrow;   // in [0,128)
#pragma unroll
            for (int h = 0; h < 2; h++)
#pragma unroll
                for (int r = 0; r < 4; r++) {
                    int node = base + h * 16 + quad * 4 + r;
                    g2b[(size_t)(col >> 5) * ((size_t)NNP * 32) + (size_t)node * 32 + (col & 31)]
                        = f2fp8(acc[h][ctl][r]);
                }
        }
    } else {
#pragma unroll
        for (int ctl = 0; ctl < 4; ctl++) {
            int pcol = cg * 64 + ctl * 16 + mrow - 128;   // in [0,128)
#pragma unroll
            for (int h = 0; h < 2; h++)
#pragma unroll
                for (int r = 0; r < 4; r++) {
                    int node = base + h * 16 + quad * 4 + r;
                    __half hf = __float2half(acc[h][ctl][r] + bias[ctl]);
                    pslc[(size_t)(pcol >> 5) * NN32 + (size_t)node * 32 + (pcol & 31)]
                        = __half_as_ushort(hf);
                }
        }
    }
}

extern "C" void kernel_launch(void* const* d_in, const int* in_sizes, int n_in,
                              void* d_out, int out_size, void* d_ws, size_t ws_size,
                              hipStream_t stream) {
    const float* x   = (const float*)d_in[0];
    const int*   ei  = (const int*)d_in[1];
    const float* W1l = (const float*)d_in[2];
    const float* b1  = (const float*)d_in[3];
    const float* W1r = (const float*)d_in[4];
    const float* W2l = (const float*)d_in[5];
    const float* b2  = (const float*)d_in[6];
    const float* W2r = (const float*)d_in[7];
    float* out = (float*)d_out;

    char* p = (char*)d_ws;
    unsigned int* axb = (unsigned int*)p; p += (size_t)NN * 256 * 2;  // [agg(128) | x(128)] bf16
    unsigned short* h = (unsigned short*)p; p += (size_t)NN * 256 * 2;
    unsigned char* g2 = (unsigned char*)p; p += (size_t)4 * NNP * 32;   // fp8, slice-major
    unsigned short* xf8s = (unsigned short*)p; p += (size_t)4 * NNP * 32; // fp8 x, slice-major
    unsigned short* wb1 = (unsigned short*)p; p += 65536 * 2;
    unsigned short* wb2 = (unsigned short*)p; p += 65536 * 2;
    int* deg  = (int*)p; p += (size_t)NN * 4;
    int* off  = (int*)p; p += (size_t)NN * 4;
    int* csr  = (int*)p; p += (size_t)NE * 4;
    int* bcnt = (int*)p; p += NB * 4;
    int* boff = (int*)p; p += (NB + 1) * 4;
    int* bcur = (int*)p; p += NB * 4;
    if (ws_size < (size_t)(p - (char*)d_ws)) return;
    // dense first-32 table (fast agg path) -- only if workspace allows
    int* csr32 = (int*)p; p += (size_t)NN * 32 * 4;
    if (ws_size < (size_t)(p - (char*)d_ws)) csr32 = nullptr;
    unsigned int* pairs = (unsigned int*)h;       // overlay: dead before gemm1 writes h
    unsigned short* pslc = (unsigned short*)axb;  // overlay: axb dead after gemm1 reads it

    hipMemsetAsync(bcnt, 0, NB * 4, stream);
    k_prep<<<3510, 256, 0, stream>>>(x, W1l, W1r, W2l, W2r, ei, axb, xf8s, wb1, wb2, bcnt,
                                     (unsigned short*)g2);
    k_bscan<<<1, NB, 0, stream>>>(bcnt, boff, bcur);
    k_bscatter<<<NCH, 256, 0, stream>>>(ei, bcur, pairs);
    k_build<<<NB, 256, 0, stream>>>(pairs, boff, off, deg, csr, csr32);
    k_agg1<<<12504, 512, 0, stream>>>(xf8s, off, deg, csr, csr32, axb);
    k_gemm1<<<GGRID, 256, 0, stream>>>((const unsigned short*)axb, wb1, b1, h);
    k_gemm2<<<GGRID, 256, 0, stream>>>(h, wb2, b2, g2, pslc);
    k_agg2<<<12504, 512, 0, stream>>>((const unsigned short*)g2, off, deg, csr, csr32, pslc, out);
}

// Round 7
// 361.079 us; speedup vs baseline: 1.1373x; 1.1373x over previous
//
#include <hip/hip_runtime.h>
#include <hip/hip_bf16.h>
#include <hip/hip_fp16.h>

#define NN 100000
#define NE 1600000
#define NCHUNK ((NN + 127) / 128)   // 782 (gemm row chunks of 128)
#define NPB 512                      // nodes per bucket (pow2, shift 9)
#define NB 256                       // bucket slots (196 active)
#define CHUNK 8192                   // edges per bscatter block
#define NCH ((NE + CHUNK - 1) / CHUNK)  // 196

typedef __attribute__((ext_vector_type(8))) short short8;
typedef __attribute__((ext_vector_type(4))) float float4v;
typedef __attribute__((ext_vector_type(2))) float float2v;

__device__ __forceinline__ unsigned short f2bf(float f) {
    unsigned int b = __float_as_uint(f);
    return (unsigned short)((b + 0x7fffu + ((b >> 16) & 1u)) >> 16);
}
__device__ __forceinline__ unsigned int pack_bf16(float lo, float hi) {
    return (unsigned int)f2bf(lo) | ((unsigned int)f2bf(hi) << 16);
}
__device__ __forceinline__ unsigned char f2fp8(float v) {
    int r = __builtin_amdgcn_cvt_pk_fp8_f32(v, v, 0, false);
    return (unsigned char)(r & 0xff);
}
__device__ __forceinline__ unsigned short pack2fp8(float lo, float hi) {
    int r = __builtin_amdgcn_cvt_pk_fp8_f32(lo, hi, 0, false);
    return (unsigned short)(r & 0xffff);
}
__device__ __forceinline__ float h2f(unsigned short u) {
    return __half2float(__ushort_as_half(u));
}

// ---- fused prep: xconv (0..3124), wconv (3125..3252), bcount (3253..3508), zero-rows (3509) ----
__global__ void k_prep(const float* x, const float* W1l, const float* W1r,
                       const float* W2l, const float* W2r, const int* ei,
                       unsigned int* axb_u, unsigned short* xf8, unsigned short* wb1,
                       unsigned short* wb2, int* bcnt, unsigned short* gz) {
    __shared__ int hh[NB];
    int b = blockIdx.x, t = threadIdx.x;
    if (b < 3125) {
#pragma unroll
        for (int k = 0; k < 8; k++) {
            int tt = b * 2048 + k * 256 + t;      // < 6.4M = NN*64
            int node = tt >> 6, i = tt & 63;
            float2 v = ((const float2*)x)[tt];
            axb_u[(size_t)node * 128 + 64 + i] = pack_bf16(v.x, v.y);
            xf8[(size_t)node * 64 + i] = pack2fp8(v.x, v.y);
        }
    } else if (b < 3253) {
        int i = (b - 3125) * 256 + t;         // < 32768
        int r1 = i >> 7, c1 = i & 127;        // W1l/W1r are 256x128
        wb1[r1 * 256 + c1]       = f2bf(W1l[i]);
        wb1[r1 * 256 + 128 + c1] = f2bf(W1r[i]);
        wb2[i]         = f2bf(W2l[i]);        // 128x256, k contiguous
        wb2[32768 + i] = f2bf(W2r[i]);
    } else if (b < 3509) {
        hh[t] = 0;
        __syncthreads();
        int e0 = (b - 3253) * 6250;           // 256 * 6250 = NE exactly
        for (int e = e0 + t; e < e0 + 6250; e += 256)
            atomicAdd(&hh[ei[NE + e] >> 9], 1);
        __syncthreads();
        if (hh[t]) atomicAdd(&bcnt[t], hh[t]);
    } else {
        // zero padding row (index NN) of xf8 and g: gather target for padded slots
        if (t < 64) xf8[(size_t)NN * 64 + t] = 0;
        else if (t < 128 && gz) gz[(size_t)NN * 64 + (t - 64)] = 0;
    }
}

__global__ void k_bscan(const int* bcnt, int* boff, int* bcur) {
    __shared__ int s[NB];
    int t = threadIdx.x;
    int v = bcnt[t];
    s[t] = v;
    __syncthreads();
    for (int d = 1; d < NB; d <<= 1) {
        int val = (t >= d) ? s[t - d] : 0;
        __syncthreads();
        s[t] += val;
        __syncthreads();
    }
    boff[t + 1] = s[t];
    if (t == 0) boff[0] = 0;
    bcur[t] = s[t] - v;   // exclusive
}

// pairs packed: bits[0:17)=row, bits[17:26)=col&511 (bucket-local)
__global__ __launch_bounds__(256) void k_bscatter(const int* ei, int* bcur, unsigned int* pairs) {
    __shared__ unsigned int buf[CHUNK];   // 32 KB
    __shared__ int cnt[NB];
    __shared__ int lbase[NB];
    __shared__ int lcur[NB];
    __shared__ int gpos[NB];
    int t = threadIdx.x;
    int e0 = blockIdx.x * CHUNK;
    int nedge = NE - e0; if (nedge > CHUNK) nedge = CHUNK;
    cnt[t] = 0;
    __syncthreads();
    for (int i = t; i < nedge; i += 256)
        atomicAdd(&cnt[ei[NE + e0 + i] >> 9], 1);
    __syncthreads();
    int v = cnt[t];
    lcur[t] = v;
    __syncthreads();
    for (int d = 1; d < NB; d <<= 1) {
        int val = (t >= d) ? lcur[t - d] : 0;
        __syncthreads();
        lcur[t] += val;
        __syncthreads();
    }
    lbase[t] = lcur[t] - v;
    gpos[t] = atomicAdd(&bcur[t], v);
    __syncthreads();
    lcur[t] = lbase[t];
    __syncthreads();
    for (int i = t; i < nedge; i += 256) {
        int r = ei[e0 + i], c = ei[NE + e0 + i];
        int b = c >> 9;
        int p = atomicAdd(&lcur[b], 1);
        buf[p] = (unsigned)r | ((unsigned)(c & 511) << 17);
    }
    __syncthreads();
    // coalesced flush: wave wv handles buckets wv, wv+4, ...; lanes stride inside
    int wv = t >> 6, lane = t & 63;
    for (int b = wv; b < NB; b += 4) {
        int n = cnt[b], lb = lbase[b], gp = gpos[b];
        for (int i = lane; i < n; i += 64)
            pairs[gp + i] = buf[lb + i];
    }
}

// builds CSR; writes dense first-32 table csr32[n][32], NN-padded to next multiple of 8
__global__ __launch_bounds__(256) void k_build(const unsigned int* pairs, const int* boff,
                                               int* off, int* deg, int* csr, int* csr32) {
    __shared__ int ldeg[NPB];
    __shared__ int lcur[NPB];
    __shared__ int lini[NPB];
    __shared__ int sscan[256];
    int b = blockIdx.x;
    int nbase = b * NPB;
    if (nbase >= NN) return;
    int t = threadIdx.x;
    int base = boff[b], cntb = boff[b + 1] - base;
    ldeg[t] = 0; ldeg[t + 256] = 0;
    __syncthreads();
    for (int i = t; i < cntb; i += 256) {
        unsigned int pr = pairs[base + i];
        atomicAdd(&ldeg[pr >> 17], 1);
    }
    __syncthreads();
    int d0 = ldeg[2 * t], d1 = ldeg[2 * t + 1];
    int v = d0 + d1;
    sscan[t] = v;
    __syncthreads();
    for (int d = 1; d < 256; d <<= 1) {
        int val = (t >= d) ? sscan[t - d] : 0;
        __syncthreads();
        sscan[t] += val;
        __syncthreads();
    }
    int ex = sscan[t] - v;
    lcur[2 * t] = ex;      lcur[2 * t + 1] = ex + d0;
    lini[2 * t] = ex;      lini[2 * t + 1] = ex + d0;
    __syncthreads();
    int nloc = NN - nbase; if (nloc > NPB) nloc = NPB;
    for (int ln = t; ln < nloc; ln += 256) {
        off[nbase + ln] = base + lcur[ln];
        deg[nbase + ln] = ldeg[ln];
    }
    __syncthreads();
    if (csr32) {
        // sentinel-pad csr32 rows: slots [deg, roundup8(deg)) -> NN (zeroed pad row)
        for (int ln = t; ln < nloc; ln += 256) {
            int dd = ldeg[ln];
            if (dd < 32) {
                int dq = (dd + 7) & ~7;
                for (int rk = dd; rk < dq; rk++)
                    csr32[(size_t)(nbase + ln) * 32 + rk] = NN;
            }
        }
        for (int i = t; i < cntb; i += 256) {
            unsigned int pr = pairs[base + i];
            int nd = pr >> 17;
            int p = atomicAdd(&lcur[nd], 1);
            int src = (int)(pr & 0x1FFFFu);
            csr[base + p] = src;
            int rk = p - lini[nd];
            if (rk < 32) csr32[(size_t)(nbase + nd) * 32 + rk] = src;
        }
    } else {
        for (int i = t; i < cntb; i += 256) {
            unsigned int pr = pairs[base + i];
            int p = atomicAdd(&lcur[pr >> 17], 1);
            csr[base + p] = (int)(pr & 0x1FFFFu);
        }
    }
}

// ---- agg1: lane=feature-pair; wave=node; degree-adaptive branch-free chunks of 8 slots ----
// mean of xf8 (fp8) over neighbors -> axb cols 0..127 (bf16)
__global__ __launch_bounds__(512) void k_agg1(const unsigned short* xf8, const int* off,
                                              const int* deg, const int* csr, const int* csr32,
                                              unsigned int* axb_w) {
    int wid = (blockIdx.x * 512 + threadIdx.x) >> 6;
    if (wid >= NN) return;
    int widu = __builtin_amdgcn_readfirstlane(wid);
    int lane = threadIdx.x & 63;
    int d = deg[widu];
    float a0 = 0.f, a1 = 0.f;
    if (csr32) {
        const int* c32 = csr32 + (size_t)widu * 32;
        int dm = d < 32 ? d : 32;
        int dq = (dm + 7) & ~7;            // wave-uniform chunk bound (NN-padded slots)
        for (int c = 0; c < dq; c += 8) {
#pragma unroll
            for (int r = 0; r < 8; r++) {
                int idx = c32[c + r];       // uniform; padded slots point at zero row
                unsigned short u = xf8[(size_t)idx * 64 + lane];
                float2v f = __builtin_amdgcn_cvt_pk_f32_fp8((unsigned int)u, false);
                a0 += f.x; a1 += f.y;
            }
        }
        if (d > 32) {
            int start = off[widu];
            for (int j = 32; j < d; j++) {
                int idx = csr[start + j];
                unsigned short u = xf8[(size_t)idx * 64 + lane];
                float2v f = __builtin_amdgcn_cvt_pk_f32_fp8((unsigned int)u, false);
                a0 += f.x; a1 += f.y;
            }
        }
    } else {
        int start = off[widu];
        for (int j = 0; j < d; j++) {
            int idx = csr[start + j];
            unsigned short u = xf8[(size_t)idx * 64 + lane];
            float2v f = __builtin_amdgcn_cvt_pk_f32_fp8((unsigned int)u, false);
            a0 += f.x; a1 += f.y;
        }
    }
    float inv = 1.0f / (float)(d > 0 ? d : 1);
    axb_w[(size_t)wid * 128 + lane] = pack_bf16(a0 * inv, a1 * inv);
}

// ---- agg2: lane=feature-pair; out = partial(f16) + mean of g (fp8) over neighbors ----
__global__ __launch_bounds__(512) void k_agg2(const unsigned short* g, const int* off,
                                              const int* deg, const int* csr, const int* csr32,
                                              const unsigned short* partial, float* out) {
    int wid = (blockIdx.x * 512 + threadIdx.x) >> 6;
    if (wid >= NN) return;
    int widu = __builtin_amdgcn_readfirstlane(wid);
    int lane = threadIdx.x & 63;
    int d = deg[widu];
    // hoist partial (f16 pair) -- overlaps the gather latency
    unsigned int pu = *(const unsigned int*)(partial + (size_t)widu * 128 + (lane << 1));
    float a0 = 0.f, a1 = 0.f;
    if (csr32) {
        const int* c32 = csr32 + (size_t)widu * 32;
        int dm = d < 32 ? d : 32;
        int dq = (dm + 7) & ~7;
        for (int c = 0; c < dq; c += 8) {
#pragma unroll
            for (int r = 0; r < 8; r++) {
                int idx = c32[c + r];
                unsigned short u = g[(size_t)idx * 64 + lane];
                float2v f = __builtin_amdgcn_cvt_pk_f32_fp8((unsigned int)u, false);
                a0 += f.x; a1 += f.y;
            }
        }
        if (d > 32) {
            int start = off[widu];
            for (int j = 32; j < d; j++) {
                int idx = csr[start + j];
                unsigned short u = g[(size_t)idx * 64 + lane];
                float2v f = __builtin_amdgcn_cvt_pk_f32_fp8((unsigned int)u, false);
                a0 += f.x; a1 += f.y;
            }
        }
    } else {
        int start = off[widu];
        for (int j = 0; j < d; j++) {
            int idx = csr[start + j];
            unsigned short u = g[(size_t)idx * 64 + lane];
            float2v f = __builtin_amdgcn_cvt_pk_f32_fp8((unsigned int)u, false);
            a0 += f.x; a1 += f.y;
        }
    }
    float inv = 1.0f / (float)(d > 0 ? d : 1);
    float2 o;
    o.x = h2f((unsigned short)(pu & 0xffff)) + a0 * inv;
    o.y = h2f((unsigned short)(pu >> 16)) + a1 * inv;
    *(float2*)(out + (size_t)wid * 128 + (lane << 1)) = o;
}

// ---- GEMM1 (col-split, XCD-swizzled): 128 rows x 64 cols of relu(A@wb1^T + b1) -> H ----
// b = (c&7) | cg<<3 | (c>>3)<<5  => the 4 cg-blocks of chunk c share an XCD (b mod 8 equal)
#define BROW 264
#define GGRID (32 * ((NCHUNK + 7) / 8))   // 32*98 = 3136
__global__ __launch_bounds__(256, 4) void k_gemm1(const unsigned short* A, const unsigned short* wb,
                                                  const float* b1, unsigned short* H) {
    __shared__ unsigned short Bs[64 * BROW];   // 33 KB
    int t = threadIdx.x;
    int b = blockIdx.x;
    int chunk = (b & 7) + ((b >> 5) << 3);
    int cg = (b >> 3) & 3;
    if (chunk >= NCHUNK) return;
    {
        const short8* src = (const short8*)(wb + (size_t)cg * 64 * 256);
        short8* dst = (short8*)Bs;   // 33 granules per row
#pragma unroll
        for (int i = 0; i < 8; i++) {
            int gi = i * 256 + t;             // 2048 granules of 16B
            int r = gi >> 5, c = gi & 31;
            dst[r * 33 + c] = src[gi];
        }
    }
    __syncthreads();
    int wv = t >> 6, lane = t & 63;
    int mrow = lane & 15, quad = lane >> 4;
    int base = chunk * 128 + wv * 32;
    if (base >= NN) return;
    float bias[4];
#pragma unroll
    for (int ctl = 0; ctl < 4; ctl++) bias[ctl] = b1[cg * 64 + ctl * 16 + mrow];
    float4v acc[2][4];
#pragma unroll
    for (int h = 0; h < 2; h++)
#pragma unroll
        for (int ctl = 0; ctl < 4; ctl++) acc[h][ctl] = (float4v)(0.0f);
    const short8* a0p = (const short8*)(A + (size_t)(base + mrow) * 256);
    const short8* a1p = (const short8*)(A + (size_t)(base + 16 + mrow) * 256);
#pragma unroll
    for (int kk = 0; kk < 8; kk++) {
        short8 a0 = a0p[kk * 4 + quad];
        short8 a1 = a1p[kk * 4 + quad];
        int koff = kk * 32 + quad * 8;
#pragma unroll
        for (int ctl = 0; ctl < 4; ctl++) {
            short8 bfr = *(const short8*)(Bs + (ctl * 16 + mrow) * BROW + koff);
            acc[0][ctl] = __builtin_amdgcn_mfma_f32_16x16x32_bf16(a0, bfr, acc[0][ctl], 0, 0, 0);
            acc[1][ctl] = __builtin_amdgcn_mfma_f32_16x16x32_bf16(a1, bfr, acc[1][ctl], 0, 0, 0);
        }
    }
#pragma unroll
    for (int ctl = 0; ctl < 4; ctl++) {
        int col = cg * 64 + ctl * 16 + mrow;
#pragma unroll
        for (int h = 0; h < 2; h++)
#pragma unroll
            for (int r = 0; r < 4; r++) {
                int node = base + h * 16 + quad * 4 + r;
                float v = acc[h][ctl][r] + bias[ctl];
                H[(size_t)node * 256 + col] = f2bf(fmaxf(v, 0.f));
            }
    }
}

// ---- GEMM2 (col-split, XCD-swizzled): cg 0,1 -> g (fp8); cg 2,3 -> partial f16 (+b2) ----
__global__ __launch_bounds__(256, 4) void k_gemm2(const unsigned short* A, const unsigned short* wb,
                                                  const float* b2, unsigned char* g,
                                                  unsigned short* partial) {
    __shared__ unsigned short Bs[64 * BROW];   // 33 KB
    int t = threadIdx.x;
    int b = blockIdx.x;
    int chunk = (b & 7) + ((b >> 5) << 3);
    int cg = (b >> 3) & 3;
    if (chunk >= NCHUNK) return;
    {
        const short8* src = (const short8*)(wb + (size_t)cg * 64 * 256);
        short8* dst = (short8*)Bs;
#pragma unroll
        for (int i = 0; i < 8; i++) {
            int gi = i * 256 + t;
            int r = gi >> 5, c = gi & 31;
            dst[r * 33 + c] = src[gi];
        }
    }
    __syncthreads();
    int wv = t >> 6, lane = t & 63;
    int mrow = lane & 15, quad = lane >> 4;
    int base = chunk * 128 + wv * 32;
    if (base >= NN) return;
    float bias[4];
#pragma unroll
    for (int ctl = 0; ctl < 4; ctl++)
        bias[ctl] = (cg >= 2) ? b2[cg * 64 + ctl * 16 + mrow - 128] : 0.f;
    float4v acc[2][4];
#pragma unroll
    for (int h = 0; h < 2; h++)
#pragma unroll
        for (int ctl = 0; ctl < 4; ctl++) acc[h][ctl] = (float4v)(0.0f);
    const short8* a0p = (const short8*)(A + (size_t)(base + mrow) * 256);
    const short8* a1p = (const short8*)(A + (size_t)(base + 16 + mrow) * 256);
#pragma unroll
    for (int kk = 0; kk < 8; kk++) {
        short8 a0 = a0p[kk * 4 + quad];
        short8 a1 = a1p[kk * 4 + quad];
        int koff = kk * 32 + quad * 8;
#pragma unroll
        for (int ctl = 0; ctl < 4; ctl++) {
            short8 bfr = *(const short8*)(Bs + (ctl * 16 + mrow) * BROW + koff);
            acc[0][ctl] = __builtin_amdgcn_mfma_f32_16x16x32_bf16(a0, bfr, acc[0][ctl], 0, 0, 0);
            acc[1][ctl] = __builtin_amdgcn_mfma_f32_16x16x32_bf16(a1, bfr, acc[1][ctl], 0, 0, 0);
        }
    }
    if (cg < 2) {
#pragma unroll
        for (int ctl = 0; ctl < 4; ctl++) {
            int col = cg * 64 + ctl * 16 + mrow;   // in [0,128)
#pragma unroll
            for (int h = 0; h < 2; h++)
#pragma unroll
                for (int r = 0; r < 4; r++) {
                    int node = base + h * 16 + quad * 4 + r;
                    g[(size_t)node * 128 + col] = f2fp8(acc[h][ctl][r]);
                }
        }
    } else {
#pragma unroll
        for (int ctl = 0; ctl < 4; ctl++) {
            int pcol = cg * 64 + ctl * 16 + mrow - 128;   // in [0,128)
#pragma unroll
            for (int h = 0; h < 2; h++)
#pragma unroll
                for (int r = 0; r < 4; r++) {
                    int node = base + h * 16 + quad * 4 + r;
                    __half hf = __float2half(acc[h][ctl][r] + bias[ctl]);
                    partial[(size_t)node * 128 + pcol] = __half_as_ushort(hf);
                }
        }
    }
}

extern "C" void kernel_launch(void* const* d_in, const int* in_sizes, int n_in,
                              void* d_out, int out_size, void* d_ws, size_t ws_size,
                              hipStream_t stream) {
    const float* x   = (const float*)d_in[0];
    const int*   ei  = (const int*)d_in[1];
    const float* W1l = (const float*)d_in[2];
    const float* b1  = (const float*)d_in[3];
    const float* W1r = (const float*)d_in[4];
    const float* W2l = (const float*)d_in[5];
    const float* b2  = (const float*)d_in[6];
    const float* W2r = (const float*)d_in[7];
    float* out = (float*)d_out;

    char* p = (char*)d_ws;
    unsigned int* axb = (unsigned int*)p; p += (size_t)NN * 256 * 2;  // [agg(128) | x(128)] bf16
    unsigned short* h = (unsigned short*)p; p += (size_t)NN * 256 * 2;
    unsigned char* g  = (unsigned char*)p; p += (size_t)NN * 128 + 256;  // fp8 e4m3 (+pad row NN)
    unsigned short* xf8 = (unsigned short*)p; p += (size_t)NN * 128 + 256; // fp8 copy of x (+pad row)
    unsigned short* wb1 = (unsigned short*)p; p += 65536 * 2;
    unsigned short* wb2 = (unsigned short*)p; p += 65536 * 2;
    int* deg  = (int*)p; p += (size_t)NN * 4;
    int* off  = (int*)p; p += (size_t)NN * 4;
    int* csr  = (int*)p; p += (size_t)NE * 4;
    int* bcnt = (int*)p; p += NB * 4;
    int* boff = (int*)p; p += (NB + 1) * 4;
    int* bcur = (int*)p; p += NB * 4;
    if (ws_size < (size_t)(p - (char*)d_ws)) return;
    // dense first-32 table (fast agg path) -- only if workspace allows
    int* csr32 = (int*)p; p += (size_t)NN * 32 * 4;
    if (ws_size < (size_t)(p - (char*)d_ws)) csr32 = nullptr;
    unsigned int* pairs = (unsigned int*)h;       // overlay: dead before gemm1 writes h
    unsigned short* partial = (unsigned short*)axb; // overlay: axb dead after gemm1 reads it

    hipMemsetAsync(bcnt, 0, NB * 4, stream);
    k_prep<<<3510, 256, 0, stream>>>(x, W1l, W1r, W2l, W2r, ei, axb, xf8, wb1, wb2, bcnt,
                                     (unsigned short*)g);
    k_bscan<<<1, NB, 0, stream>>>(bcnt, boff, bcur);
    k_bscatter<<<NCH, 256, 0, stream>>>(ei, bcur, pairs);
    k_build<<<NB, 256, 0, stream>>>(pairs, boff, off, deg, csr, csr32);
    k_agg1<<<12500, 512, 0, stream>>>(xf8, off, deg, csr, csr32, axb);
    k_gemm1<<<GGRID, 256, 0, stream>>>((const unsigned short*)axb, wb1, b1, h);
    k_gemm2<<<GGRID, 256, 0, stream>>>(h, wb2, b2, g, partial);
    k_agg2<<<12500, 512, 0, stream>>>((const unsigned short*)g, off, deg, csr, csr32, partial, out);
}